// Round 12
// baseline (50.328 us; speedup 1.0000x reference)
//
#include <hip/hip_runtime.h>
#include <stdint.h>

// Problem geometry (fixed by reference):
//   preds      [8, 21, 512, 512] f32
//   embeddings [8, 128, 128, 128] f32
//   gts        [8, 512, 512] i32  (unused)
//   fsss_gts   [8, 512, 512] i32
//   pos_memory [1000, 128] f32
//   neg_memory [1000, 128] f32
//   out: scalar f32
// Downsample 512->128 nearest picks rows/cols 4i, 4j exactly.
//
// Ledger of structural findings:
//  R3/R9: ANY device-wide barrier where blocks WAIT costs >100us on MI355X.
//      Fire-and-forget completion-counter finisher (non-finishers EXIT) ~5us.
//  R4: owner-block selection (ballot + redundant prefix) is the right shape.
//  R6: serial single-block global walks = ~125us -> banned.
//  R7 vs R8 (same-container A/B): NT loads on preds/fsss ~11us faster.
//  R7 vs R10: dispatch boundary on this container is only ~1-2us.
//  R10->R11: problem has only 2048 waves at 1 thread/position = 25% occupancy;
//      mask kernel is latency-throttled. Split channels across 4 waves ->
//      8192 waves (100% occ), pm = (max over c>=1) > v[c0] (no argmax index).
//  R11 bench was an infra failure (container died pre-push, 3rd time);
//      resubmitting unchanged.

#define NPOS   131072  // 8*128*128
#define NBLK1  2048    // K1 grid: 64 positions per block
#define MEMSZ  1000
#define KANC   100     // MEM/10
#define KPN    333     // MEM/3
#define SLOT_POS 100
#define SLOT_NEG 433
#define FIX_SCALE 1099511627776.0        // 2^40
#define INV_FIX   (1.0 / 1099511627776.0)

// ws byte layout
#define OFF_FLAGS   0          // 131072 B
#define OFF_COUNTS  131072     // 3*2048*4 = 24576 B
#define OFF_ACCUM   155648     // 4*3*128*8 = 12288 B (8-aligned)
#define OFF_CTR     167936     // 4 B

// ========= K1: 4-wave channel-split mask; 64 positions/block =========
__global__ __launch_bounds__(256) void mask_kernel(
    const float* __restrict__ preds,
    const int* __restrict__ fsss,
    uint8_t* __restrict__ flags,
    int* __restrict__ blockCounts,     // [3][2048]
    unsigned long long* __restrict__ accum,
    unsigned int* __restrict__ counterB)
{
    const int tid = threadIdx.x, blk = blockIdx.x;
    const int lane = tid & 63, wave = tid >> 6;
    const int n = blk * 64 + lane;     // this lane's position (all 4 waves same n)
    const int b = n >> 14;
    const int ij = n & 16383;
    const int row = (ij >> 7) << 2;
    const int col = (ij & 127) << 2;

    const float* base = preds + (size_t)b * 21 * 262144 + (size_t)row * 512 + col;
#define LCH(c) __builtin_nontemporal_load(base + (size_t)(c) * 262144)

    __shared__ float s_rest[4][64];
    __shared__ float s_v00[64];
    float mrest;
    if (wave == 0) {
        const float v00 = LCH(0);
        s_v00[lane] = v00;
        mrest = LCH(1);
        mrest = fmaxf(mrest, LCH(2));
        mrest = fmaxf(mrest, LCH(3));
        mrest = fmaxf(mrest, LCH(4));
        mrest = fmaxf(mrest, LCH(5));
    } else if (wave == 1) {
        mrest = LCH(6);
        mrest = fmaxf(mrest, LCH(7));
        mrest = fmaxf(mrest, LCH(8));
        mrest = fmaxf(mrest, LCH(9));
        mrest = fmaxf(mrest, LCH(10));
    } else if (wave == 2) {
        mrest = LCH(11);
        mrest = fmaxf(mrest, LCH(12));
        mrest = fmaxf(mrest, LCH(13));
        mrest = fmaxf(mrest, LCH(14));
        mrest = fmaxf(mrest, LCH(15));
    } else {
        mrest = LCH(16);
        mrest = fmaxf(mrest, LCH(17));
        mrest = fmaxf(mrest, LCH(18));
        mrest = fmaxf(mrest, LCH(19));
        mrest = fmaxf(mrest, LCH(20));
    }
#undef LCH
    s_rest[wave][lane] = mrest;
    __syncthreads();

    if (wave == 0) {
        const float mr = fmaxf(fmaxf(s_rest[0][lane], s_rest[1][lane]),
                               fmaxf(s_rest[2][lane], s_rest[3][lane]));
        const bool pm = mr > s_v00[lane];          // argmax != 0  (strict first-max)
        const int fv = __builtin_nontemporal_load(
            fsss + (size_t)b * 262144 + (size_t)row * 512 + col);
        const bool fm = (fv != 0) && (fv != 255);
        const int myflag = (int)(pm && fm)                // bit0: anchor
                         | ((int)(!pm && fm) << 1)        // bit1: positive
                         | ((int)(pm && (fv == 0)) << 2); // bit2: negative
        flags[n] = (uint8_t)myflag;

        const int ca = (int)__popcll(__ballot(myflag & 1));
        const int cb = (int)__popcll(__ballot((myflag >> 1) & 1));
        const int cc = (int)__popcll(__ballot((myflag >> 2) & 1));
        if (lane == 0)      blockCounts[blk]            = ca;
        else if (lane == 1) blockCounts[NBLK1 + blk]    = cb;
        else if (lane == 2) blockCounts[2 * NBLK1 + blk] = cc;
    }

    // zero accum + K2's completion counter every replay (K2 runs after K1)
    if (blk == 0) {
        for (int i = tid; i < 4 * 3 * 128; i += 256) accum[i] = 0ull;
        if (tid == 0) *counterB = 0u;
    }
}

// ====== K2: redundant prefix scan + parallel slot inversion + gather + finisher ======
// blocks 0..382: 2 slots each.  blocks 383..398: untouched-memory-row tails.
__global__ __launch_bounds__(256) void select_gather_final_kernel(
    const float* __restrict__ emb,
    const float* __restrict__ posMem,
    const float* __restrict__ negMem,
    const uint8_t* __restrict__ flags,
    const int* __restrict__ blockCounts,
    unsigned long long* __restrict__ accum,   // [4 shadows][3 cats][128]
    unsigned int* __restrict__ counterB,
    float* __restrict__ out)
{
    const int tid = threadIdx.x, blk = blockIdx.x;
    const int lane = tid & 63, wave = tid >> 6;
    const int d = tid & 127;

    // ---- exclusive prefix over [3][2048] counts, redundant per block ----
    __shared__ int s_pre[3 * NBLK1];   // 24 KB
    __shared__ int s_tot[3];
    __shared__ int s_w[4];
#pragma unroll 1
    for (int cat = 0; cat < 3; ++cat) {
        int e[8]; int sum = 0;
#pragma unroll
        for (int k = 0; k < 8; ++k) {
            e[k] = blockCounts[cat * NBLK1 + tid * 8 + k];
            sum += e[k];
        }
        int incl = sum;
#pragma unroll
        for (int off = 1; off < 64; off <<= 1) {
            int v = __shfl_up(incl, off, 64);
            if (lane >= off) incl += v;
        }
        if (lane == 63) s_w[wave] = incl;
        __syncthreads();
        int woff = 0;
#pragma unroll
        for (int w = 0; w < 4; ++w) if (w < wave) woff += s_w[w];
        int run = woff + incl - sum;
#pragma unroll
        for (int k = 0; k < 8; ++k) {
            s_pre[cat * NBLK1 + tid * 8 + k] = run;
            run += e[k];
        }
        if (tid == 0) s_tot[cat] = s_w[0] + s_w[1] + s_w[2] + s_w[3];
        __syncthreads();
    }
    const int A = min(KANC, s_tot[0]);
    const int P = min(KPN, s_tot[1]);
    const int Q = min(KPN, s_tot[2]);

    if (blk < 383) {
        // ---- invert the first-k map: wave 0 -> slot h=0, wave 1 -> h=1 ----
        __shared__ int s_nn[2];
        if (tid < 2) s_nn[tid] = -1;
        __syncthreads();
        if (wave < 2) {
            const int h = wave;
            const int slot = blk * 2 + h;
            int cat, r;
            if (slot < SLOT_POS)      { cat = 0; r = slot; }
            else if (slot < SLOT_NEG) { cat = 1; r = slot - SLOT_POS; }
            else                      { cat = 2; r = slot - SLOT_NEG; }
            const int cnt = (cat == 0) ? A : ((cat == 1) ? P : Q);
            if (r < cnt) {
                // largest bb with pre[cat][bb] <= r (wave-uniform binsearch, 11 iters)
                int lo = 0, hi = NBLK1 - 1;
                while (lo < hi) {
                    const int mid = (lo + hi + 1) >> 1;
                    if (s_pre[cat * NBLK1 + mid] <= r) lo = mid; else hi = mid - 1;
                }
                const int bb = lo;
                const int lr = r - s_pre[cat * NBLK1 + bb];
                // single-wave ballot-rank over the owner's 64 flags
                const int bit = (flags[bb * 64 + lane] >> cat) & 1;
                const unsigned long long m = __ballot(bit);
                const int intra = (int)__popcll(m & ((1ull << lane) - 1ull));
                if (bit && intra == lr) s_nn[h] = bb * 64 + lane;
            }
        }
        __syncthreads();

        // ---- gather + normalize both slots (half per slot) ----
        const int half = tid >> 7;
        const int slot = blk * 2 + half;
        const int cat = (slot < SLOT_POS) ? 0 : ((slot < SLOT_NEG) ? 1 : 2);
        const int nn = s_nn[half];
        float v = 0.f;
        if (nn >= 0)
            v = emb[((size_t)(nn >> 14) * 128 + d) * 16384 + (nn & 16383)];
        float sq = v * v;
#pragma unroll
        for (int off = 1; off < 64; off <<= 1) sq += __shfl_xor(sq, off, 64);
        __shared__ float s_f[4];
        if (lane == 0) s_f[wave] = sq;   // waves 0,1 = half0; waves 2,3 = half1
        __syncthreads();
        const float nrm2 = s_f[half * 2] + s_f[half * 2 + 1];
        if (nn >= 0) {
            const float scale = 1.0f / fmaxf(sqrtf(nrm2), 1e-12f);
            const long long fx =
                (long long)llrint((double)v * (double)scale * FIX_SCALE);
            atomicAdd(&accum[(((blk & 3) * 3 + cat) << 7) + d],
                      (unsigned long long)fx);
        }
    } else {
        // ---- untouched-memory-row tails ----
        const int t = blk - 383;
        const int memSel = t >> 3;            // 0=pos, 1=neg
        const int part = t & 7;
        const float* mem = memSel ? negMem : posMem;
        const int cnt = memSel ? Q : P;       // rows [0,cnt) replaced by selections
        const int rowHalf = tid >> 7;
        const int m0 = part * 125;
        double acc = 0.0;
        for (int r = rowHalf; r < 125; r += 2) {
            const int m = m0 + r;
            if (m >= cnt) acc += (double)mem[(size_t)m * 128 + d];
        }
        const long long fx = (long long)llrint(acc * FIX_SCALE);
        atomicAdd(&accum[(((blk & 3) * 3 + (memSel ? 2 : 1)) << 7) + d],
                  (unsigned long long)fx);
    }

    // ---- release, completion count (fire-and-forget finisher, proven R6-R10) ----
    __threadfence();
    __syncthreads();
    __shared__ int s_fin;
    if (tid == 0) {
        unsigned old = atomicAdd(counterB, 1u);
        s_fin = (old == 398) ? 1 : 0;
    }
    __syncthreads();
    if (!s_fin) return;
    __threadfence();

    // ---- finisher: final dot + relu (reads only 12KB accum) ----
    __shared__ double s_d[2];
    if (tid < 128) {
        double anc = 0.0, pos = 0.0, neg = 0.0;
#pragma unroll
        for (int s = 0; s < 4; ++s) {
            anc += (double)(long long)accum[((s * 3 + 0) << 7) + tid];
            pos += (double)(long long)accum[((s * 3 + 1) << 7) + tid];
            neg += (double)(long long)accum[((s * 3 + 2) << 7) + tid];
        }
        double prod = anc * (pos - neg) * (INV_FIX * INV_FIX);
#pragma unroll
        for (int off = 1; off < 64; off <<= 1) prod += __shfl_xor(prod, off, 64);
        if (lane == 0) s_d[wave] = prod;
    }
    __syncthreads();
    if (tid == 0) {
        const double red = s_d[0] + s_d[1];
        const double nAnc = (A > 0) ? (double)A : 1.0;
        const double vv = red / (nAnc * (double)MEMSZ) + 0.2;
        out[0] = (float)(vv > 0.0 ? vv : 0.0);
    }
}

extern "C" void kernel_launch(void* const* d_in, const int* in_sizes, int n_in,
                              void* d_out, int out_size, void* d_ws, size_t ws_size,
                              hipStream_t stream) {
    const float* preds  = (const float*)d_in[0];
    const float* emb    = (const float*)d_in[1];
    // d_in[2] = gts, unused by the loss
    const int* fsss     = (const int*)d_in[3];
    const float* posMem = (const float*)d_in[4];
    const float* negMem = (const float*)d_in[5];
    float* out = (float*)d_out;

    char* ws = (char*)d_ws;
    uint8_t* flags      = (uint8_t*)(ws + OFF_FLAGS);
    int* blockCounts    = (int*)(ws + OFF_COUNTS);
    unsigned long long* accum = (unsigned long long*)(ws + OFF_ACCUM);
    unsigned int* ctr   = (unsigned int*)(ws + OFF_CTR);

    mask_kernel<<<NBLK1, 256, 0, stream>>>(preds, fsss, flags, blockCounts,
                                           accum, ctr);
    select_gather_final_kernel<<<399, 256, 0, stream>>>(emb, posMem, negMem,
                                                        flags, blockCounts,
                                                        accum, ctr, out);
}